// Round 2
// baseline (260.431 us; speedup 1.0000x reference)
//
#include <hip/hip_runtime.h>
#include <math.h>

// SE4 squeeze-excite, B=8, C=64, H=W=256, 4x4 patch grid (64x64 patches), SQ=256.
// ALL I/O float32. fp32 compute.
//
// R5 = R4 with compile fix: nontemporal builtins need native vector types
// (clang ext_vector_type), not HIP_vector_type<float,4>.
//
// R4 changes vs R3: reduce/expand were latency-bound, not bandwidth-bound.
// R3 gave them 1 wave/SIMD with 144-deep (reduce) / 36-deep (expand) serial
// cold-load chains (weights are HBM-cold each iteration; L3 is flushed by the
// harness poison + t/out traffic). R4 flattens K across the whole block:
// one k per thread, 9-load chain, 16 waves/CU. Scale gets nontemporal
// loads/stores to preserve L3 residency of unread t lines.

#define Bsz 8
#define Csz 64
#define Hsz 256
#define Wsz 256
#define SQsz 256
#define C16 1024   // 16*C

typedef float f32x4 __attribute__((ext_vector_type(4)));

// ---------------- kernel 1: patch pooling ----------------
// grid = B*C*16 = 8192 blocks of 256 threads. p = bid & 15 (= i*4+j), bc = bid>>4.
// Patch: 64 rows x 64 cols fp32 = 1024 float4 groups; each thread sums 4 groups.
__global__ __launch_bounds__(256) void pool_kernel(const float* __restrict__ t,
                                                   float* __restrict__ pooled) {
    int bid = blockIdx.x;
    int p   = bid & 15;
    int bc  = bid >> 4;          // b*C + c
    int i   = p >> 2, j = p & 3;
    const float* base = t + (((size_t)bc * Hsz + (size_t)i * 64) * Wsz + (size_t)j * 64);
    int tid = threadIdx.x;
    float sum = 0.f;
#pragma unroll
    for (int k = 0; k < 4; ++k) {
        int g    = tid + k * 256;          // 0..1023
        int row  = g >> 4;
        int col4 = g & 15;
        f32x4 v = *(const f32x4*)(base + (size_t)row * Wsz + col4 * 4);
        sum += v.x + v.y + v.z + v.w;
    }
#pragma unroll
    for (int off = 32; off > 0; off >>= 1) sum += __shfl_down(sum, off, 64);
    __shared__ float wsum[4];
    if ((tid & 63) == 0) wsum[tid >> 6] = sum;
    __syncthreads();
    if (tid == 0) {
        float s = wsum[0] + wsum[1] + wsum[2] + wsum[3];
        int b = bc >> 6;          // /C
        int c = bc & 63;
        pooled[b * C16 + p * Csz + c] = s * (1.0f / 4096.0f);
    }
}

// ---------------- kernel 2: s = mish(pooled @ reduce_w^T + reduce_b) ----------------
// grid = 256 blocks (one per output o) x 1024 threads: k = tid, ONE element per
// thread. Per-wave dependent chain = 1 weight load + 8 pooled loads (vs 144 in
// R3). 16 waves/CU hide the cold-HBM weight latency. Butterfly within wave,
// LDS combine across the 16 waves, lanes 0-7 finish with bias + mish.
__global__ __launch_bounds__(1024) void reduce_kernel(const float* __restrict__ pooled,
                                                      const float* __restrict__ reduce_w,
                                                      const float* __restrict__ reduce_b,
                                                      float* __restrict__ s_out) {
    int o   = blockIdx.x;
    int tid = threadIdx.x;          // 0..1023 == k
    int w   = tid >> 6;             // wave 0..15
    int l   = tid & 63;
    float wv = reduce_w[(size_t)o * C16 + tid];
    float acc[Bsz];
#pragma unroll
    for (int b = 0; b < Bsz; ++b)
        acc[b] = wv * pooled[b * C16 + tid];
#pragma unroll
    for (int off = 32; off > 0; off >>= 1) {
#pragma unroll
        for (int b = 0; b < Bsz; ++b)
            acc[b] += __shfl_xor(acc[b], off, 64);
    }
    __shared__ float red[16][Bsz];
    if (l == 0) {
#pragma unroll
        for (int b = 0; b < Bsz; ++b) red[w][b] = acc[b];
    }
    __syncthreads();
    if (tid < Bsz) {
        float x = reduce_b[o];
#pragma unroll
        for (int q = 0; q < 16; ++q) x += red[q][tid];
        float sp = (x > 15.f) ? x : log1pf(expf(x));
        s_out[tid * SQsz + o] = x * tanhf(sp);
    }
}

// ---------------- kernel 3: g = sigmoid(s @ expand_w^T + expand_b) ----------------
// grid = 1024 blocks (one per output o) x 256 threads: k = tid, one element per
// thread, 9-load chain. 4 blocks/CU x 4 waves = 16 waves/CU.
__global__ __launch_bounds__(256) void expand_kernel(const float* __restrict__ s_in,
                                                     const float* __restrict__ expand_w,
                                                     const float* __restrict__ expand_b,
                                                     float* __restrict__ g_out) {
    int o   = blockIdx.x;
    int tid = threadIdx.x;          // 0..255 == k
    int w   = tid >> 6;             // wave 0..3
    int l   = tid & 63;
    float wv = expand_w[(size_t)o * SQsz + tid];
    float acc[Bsz];
#pragma unroll
    for (int b = 0; b < Bsz; ++b)
        acc[b] = wv * s_in[b * SQsz + tid];
#pragma unroll
    for (int off = 32; off > 0; off >>= 1) {
#pragma unroll
        for (int b = 0; b < Bsz; ++b)
            acc[b] += __shfl_xor(acc[b], off, 64);
    }
    __shared__ float red[4][Bsz];
    if (l == 0) {
#pragma unroll
        for (int b = 0; b < Bsz; ++b) red[w][b] = acc[b];
    }
    __syncthreads();
    if (tid < Bsz) {
        float x = expand_b[o] + red[0][tid] + red[1][tid] + red[2][tid] + red[3][tid];
        g_out[tid * C16 + o] = 1.0f / (1.0f + expf(-x));
    }
}

// ---------------- kernel 4: out = t * gate ----------------
// One thread per float4 (4 | 64, never crosses a patch-column boundary).
// 33,554,432/4 = 8,388,608 threads -> 32768 blocks x 256.
// Nontemporal: t lines are dead after this read; out has no reuse. Keeps
// not-yet-read t lines resident in L3 (t was loaded there by pool_kernel).
__global__ __launch_bounds__(256) void scale_kernel(const float* __restrict__ t,
                                                    const float* __restrict__ g,
                                                    float* __restrict__ out) {
    unsigned int idx = blockIdx.x * 256u + threadIdx.x;   // float4 group index
    int w4 = idx & 63;                // w/4
    int h  = (idx >> 6) & 255;
    int c  = (idx >> 14) & 63;
    int b  = idx >> 20;
    int p  = ((h >> 6) << 2) | (w4 >> 4);    // i*4 + j
    float gate = g[(b << 10) + (p << 6) + c];
    f32x4 v = __builtin_nontemporal_load((const f32x4*)(t + (size_t)idx * 4));
    f32x4 r;
    r.x = v.x * gate;
    r.y = v.y * gate;
    r.z = v.z * gate;
    r.w = v.w * gate;
    __builtin_nontemporal_store(r, (f32x4*)(out + (size_t)idx * 4));
}

extern "C" void kernel_launch(void* const* d_in, const int* in_sizes, int n_in,
                              void* d_out, int out_size, void* d_ws, size_t ws_size,
                              hipStream_t stream) {
    const float* t        = (const float*)d_in[0];
    const float* reduce_w = (const float*)d_in[1];
    const float* reduce_b = (const float*)d_in[2];
    const float* expand_w = (const float*)d_in[3];
    const float* expand_b = (const float*)d_in[4];
    float* out = (float*)d_out;

    float* pooled = (float*)d_ws;                 // 8*1024 fp32 = 32 KB
    float* s_buf  = pooled + Bsz * C16;           // 8*256  fp32 =  8 KB
    float* g_buf  = s_buf + Bsz * SQsz;           // 8*1024 fp32 = 32 KB

    pool_kernel  <<<Bsz * Csz * 16, 256, 0, stream>>>(t, pooled);
    reduce_kernel<<<SQsz,          1024, 0, stream>>>(pooled, reduce_w, reduce_b, s_buf);
    expand_kernel<<<C16,            256, 0, stream>>>(s_buf, expand_w, expand_b, g_buf);
    scale_kernel <<<32768,          256, 0, stream>>>(t, g_buf, out);
}